// Round 1
// baseline (691.197 us; speedup 1.0000x reference)
//
#include <hip/hip_runtime.h>

typedef __bf16 bf16x8 __attribute__((ext_vector_type(8)));
typedef float floatx4 __attribute__((ext_vector_type(4)));

__device__ __forceinline__ unsigned short f2bf(float f) {
    unsigned int u = __builtin_bit_cast(unsigned int, f);
    u += 0x7fffu + ((u >> 16) & 1u);   // round-to-nearest-even
    return (unsigned short)(u >> 16);
}

// ---------------- kernel 0: conv_weight -> bf16, row sums S[o] ----------------
__global__ __launch_bounds__(256) void prep_kernel(const float* __restrict__ cw,
                                                   unsigned short* __restrict__ cwb,
                                                   float* __restrict__ S) {
    int o = blockIdx.x;
    int c = threadIdx.x;
    float w = cw[o * 256 + c];
    cwb[o * 256 + c] = f2bf(w);
    float s = w;
    #pragma unroll
    for (int off = 32; off; off >>= 1) s += __shfl_xor(s, off);
    __shared__ float ps[4];
    if ((c & 63) == 0) ps[c >> 6] = s;
    __syncthreads();
    if (c == 0) S[o] = ps[0] + ps[1] + ps[2] + ps[3];
}

// ---------------- kernel 1: z = x+y, LayerNorm over W, write bf16 zhat' ----------------
// zhat'[b,c,h,w] = (z - mean) * rstd * lnw[w]   (lnb folded into GEMM epilogue)
// one wave per row of 256; 4 rows per block
__global__ __launch_bounds__(256) void ln_kernel(const float* __restrict__ x,
                                                 const float* __restrict__ y,
                                                 const float* __restrict__ lnw,
                                                 unsigned short* __restrict__ zhat) {
    int wave = threadIdx.x >> 6;
    int lane = threadIdx.x & 63;
    size_t row = (size_t)blockIdx.x * 4 + wave;   // (b*256+c)*256+h, 262144 rows
    const float4* xp = (const float4*)(x + row * 256) + lane;
    const float4* yp = (const float4*)(y + row * 256) + lane;
    float4 xv = *xp;
    float4 yv = *yp;
    float z0 = xv.x + yv.x, z1 = xv.y + yv.y, z2 = xv.z + yv.z, z3 = xv.w + yv.w;
    float s = z0 + z1 + z2 + z3;
    float q = z0 * z0 + z1 * z1 + z2 * z2 + z3 * z3;
    #pragma unroll
    for (int off = 32; off; off >>= 1) {
        s += __shfl_xor(s, off);
        q += __shfl_xor(q, off);
    }
    float mean = s * (1.0f / 256.0f);
    float var = q * (1.0f / 256.0f) - mean * mean;
    float rstd = rsqrtf(var + 1e-5f);
    float4 w4 = *((const float4*)lnw + lane);
    ushort4 ov;
    ov.x = f2bf((z0 - mean) * rstd * w4.x);
    ov.y = f2bf((z1 - mean) * rstd * w4.y);
    ov.z = f2bf((z2 - mean) * rstd * w4.z);
    ov.w = f2bf((z3 - mean) * rstd * w4.w);
    *((ushort4*)(zhat + row * 256) + lane) = ov;
}

// ---------------- kernel 2: out[b,o,p] = relu( cwb @ zhat'[b] + S[o]*lnb[p&255] ) ----------------
// per block: all 256 o  x  64 pixels, K=256.  4 waves, each 64 o x 64 px.
__global__ __launch_bounds__(256) void gemm_kernel(const unsigned short* __restrict__ zhat,
                                                   const unsigned short* __restrict__ cwb,
                                                   const float* __restrict__ S,
                                                   const float* __restrict__ lnb,
                                                   float* __restrict__ out) {
    constexpr int LDK = 264;                 // bf16 elems per LDS row: 16B-aligned, 8-clk bank floor
    __shared__ unsigned short bt[64 * LDK];  // B tile transposed: [n][k], 33 KiB

    int id = blockIdx.x;
    int b = id >> 10;          // 1024 pixel-tiles per batch
    int tile = id & 1023;
    int p0 = tile * 64;
    const unsigned short* zb = zhat + ((size_t)b << 24) + p0;  // [c][p] rows, stride 65536
    int t = threadIdx.x;

    // ---- stage B tile (256 k x 64 n) into LDS, transposed to [n][k] ----
    {
        int c0 = t >> 3;            // 0..31
        int n0 = (t & 7) * 8;       // 0..56
        #pragma unroll
        for (int pass = 0; pass < 8; ++pass) {
            int c = c0 + pass * 32;
            uint4 v = *(const uint4*)(zb + (size_t)c * 65536 + n0);  // 8 bf16 along n
            unsigned int vv[4] = {v.x, v.y, v.z, v.w};
            #pragma unroll
            for (int q = 0; q < 4; ++q) {
                bt[(n0 + 2 * q + 0) * LDK + c] = (unsigned short)(vv[q] & 0xffffu);
                bt[(n0 + 2 * q + 1) * LDK + c] = (unsigned short)(vv[q] >> 16);
            }
        }
    }
    __syncthreads();

    int wave = t >> 6;
    int lane = t & 63;
    int llo = lane & 15;
    int lhi = lane >> 4;
    int o_base = wave * 64;

    floatx4 acc[4][4];
    #pragma unroll
    for (int u = 0; u < 4; ++u)
        #pragma unroll
        for (int s = 0; s < 4; ++s)
            #pragma unroll
            for (int r = 0; r < 4; ++r) acc[u][s][r] = 0.0f;

    #pragma unroll
    for (int kt = 0; kt < 8; ++kt) {
        int k0 = kt * 32;
        bf16x8 bfrag[4], afrag[4];
        #pragma unroll
        for (int s = 0; s < 4; ++s)
            bfrag[s] = *(const bf16x8*)&bt[(16 * s + llo) * LDK + k0 + lhi * 8];
        #pragma unroll
        for (int u = 0; u < 4; ++u)
            afrag[u] = *(const bf16x8*)(cwb + (size_t)(o_base + 16 * u + llo) * 256 + k0 + lhi * 8);
        #pragma unroll
        for (int u = 0; u < 4; ++u)
            #pragma unroll
            for (int s = 0; s < 4; ++s)
                acc[u][s] = __builtin_amdgcn_mfma_f32_16x16x32_bf16(afrag[u], bfrag[s], acc[u][s], 0, 0, 0);
    }

    // ---- epilogue: + S[o]*lnb[w], relu, store ----
    float lnbv[4];
    #pragma unroll
    for (int s = 0; s < 4; ++s) lnbv[s] = lnb[(p0 + 16 * s + llo) & 255];
    float* outb = out + ((size_t)b << 24) + p0;
    #pragma unroll
    for (int u = 0; u < 4; ++u) {
        #pragma unroll
        for (int r = 0; r < 4; ++r) {
            int o = o_base + 16 * u + 4 * lhi + r;
            float so = S[o];
            #pragma unroll
            for (int s = 0; s < 4; ++s) {
                float v = acc[u][s][r] + so * lnbv[s];
                v = v > 0.0f ? v : 0.0f;
                outb[(size_t)o * 65536 + 16 * s + llo] = v;
            }
        }
    }
}

extern "C" void kernel_launch(void* const* d_in, const int* in_sizes, int n_in,
                              void* d_out, int out_size, void* d_ws, size_t ws_size,
                              hipStream_t stream) {
    const float* x   = (const float*)d_in[0];
    const float* y   = (const float*)d_in[1];
    const float* lnw = (const float*)d_in[2];
    const float* lnb = (const float*)d_in[3];
    const float* cw  = (const float*)d_in[4];
    float* out = (float*)d_out;

    // ws layout: zhat bf16 [4][256][65536] = 128 MiB | cwb bf16 128 KiB | S 1 KiB
    unsigned short* zhat = (unsigned short*)d_ws;
    unsigned short* cwb  = (unsigned short*)((char*)d_ws + (size_t)134217728);
    float* S             = (float*)((char*)d_ws + (size_t)134217728 + 131072);

    prep_kernel<<<256, 256, 0, stream>>>(cw, cwb, S);
    ln_kernel<<<65536, 256, 0, stream>>>(x, y, lnw, zhat);
    gemm_kernel<<<4096, 256, 0, stream>>>(zhat, cwb, S, lnb, out);
}

// Round 2
// 639.010 us; speedup vs baseline: 1.0817x; 1.0817x over previous
//
#include <hip/hip_runtime.h>

typedef __bf16 bf16x8 __attribute__((ext_vector_type(8)));
typedef float floatx4 __attribute__((ext_vector_type(4)));

__device__ __forceinline__ unsigned short f2bf(float f) {
    unsigned int u = __builtin_bit_cast(unsigned int, f);
    u += 0x7fffu + ((u >> 16) & 1u);   // round-to-nearest-even
    return (unsigned short)(u >> 16);
}

// ---------------- kernel 0: conv_weight -> bf16, row sums S[o] ----------------
__global__ __launch_bounds__(256) void prep_kernel(const float* __restrict__ cw,
                                                   unsigned short* __restrict__ cwb,
                                                   float* __restrict__ S) {
    int o = blockIdx.x;
    int c = threadIdx.x;
    float w = cw[o * 256 + c];
    cwb[o * 256 + c] = f2bf(w);
    float s = w;
    #pragma unroll
    for (int off = 32; off; off >>= 1) s += __shfl_xor(s, off);
    __shared__ float ps[4];
    if ((c & 63) == 0) ps[c >> 6] = s;
    __syncthreads();
    if (c == 0) S[o] = ps[0] + ps[1] + ps[2] + ps[3];
}

// ---------------- fused: z=x+y, LN over w, 1x1 conv over c (MFMA), ReLU ----------------
// block = one (b,h) plane: M=256 o, N=256 w, K=256 c. 512 threads = 8 waves.
// LDS tile zt[w][c] bf16 (128 KiB), chunk-XOR swizzled: 16B chunk index
// chunk' = chunk ^ (w&7) on a 512B row stride -> both ds_write_b128 (LN
// transpose) and ds_read_b128 (B-frags) sit at the 8-lane/4-bank-cluster floor.
__global__ __launch_bounds__(512) void fused_kernel(const float* __restrict__ x,
                                                    const float* __restrict__ y,
                                                    const float* __restrict__ lnw,
                                                    const float* __restrict__ lnb,
                                                    const unsigned short* __restrict__ cwb,
                                                    const float* __restrict__ S,
                                                    float* __restrict__ out) {
    __shared__ unsigned short zt[256 * 256];   // [w][swizzled c], 131072 B

    int b = blockIdx.x >> 8;
    int h = blockIdx.x & 255;
    int t = threadIdx.x;
    int wave = t >> 6;
    int lane = t & 63;
    size_t plane = ((size_t)b << 24) + ((size_t)h << 8);   // + c*65536 + w

    // ---- phase 1: LN. wave handles c = wave*32 .. +31, in 4 groups of 8 rows ----
    float lw[4];
    #pragma unroll
    for (int j = 0; j < 4; ++j) lw[j] = lnw[lane + 64 * j];

    #pragma unroll
    for (int g = 0; g < 4; ++g) {
        int c0 = wave * 32 + g * 8;
        unsigned short fr[4][8];   // [j: w-group][r: c within group]
        #pragma unroll
        for (int r = 0; r < 8; ++r) {
            int c = c0 + r;
            const float* xp = x + plane + ((size_t)c << 16);
            const float* yp = y + plane + ((size_t)c << 16);
            float z[4];
            float s = 0.0f, q = 0.0f;
            #pragma unroll
            for (int j = 0; j < 4; ++j) {
                float xv = xp[lane + 64 * j];
                float yv = yp[lane + 64 * j];
                z[j] = xv + yv;
                s += z[j];
                q += z[j] * z[j];
            }
            #pragma unroll
            for (int off = 32; off; off >>= 1) {
                s += __shfl_xor(s, off);
                q += __shfl_xor(q, off);
            }
            float mean = s * (1.0f / 256.0f);
            float rstd = rsqrtf(q * (1.0f / 256.0f) - mean * mean + 1e-5f);
            #pragma unroll
            for (int j = 0; j < 4; ++j) fr[j][r] = f2bf((z[j] - mean) * rstd * lw[j]);
        }
        int chunk = c0 >> 3;               // wave*4 + g
        int chunkp = chunk ^ (lane & 7);   // w&7 == lane&7
        #pragma unroll
        for (int j = 0; j < 4; ++j) {
            int w = lane + 64 * j;
            uint4 v;
            v.x = (unsigned int)fr[j][0] | ((unsigned int)fr[j][1] << 16);
            v.y = (unsigned int)fr[j][2] | ((unsigned int)fr[j][3] << 16);
            v.z = (unsigned int)fr[j][4] | ((unsigned int)fr[j][5] << 16);
            v.w = (unsigned int)fr[j][6] | ((unsigned int)fr[j][7] << 16);
            *(uint4*)&zt[w * 256 + chunkp * 8] = v;
        }
    }
    __syncthreads();

    // ---- phase 2: GEMM. wave -> o_base = (wave&3)*64, pixel tiles pt = (wave>>2)*2 + pi ----
    int llo = lane & 15;
    int lhi = lane >> 4;
    int o_base = (wave & 3) * 64;
    int ptbase = (wave >> 2) * 2;
    float* ob = out + plane;   // + o*65536 + w

    #pragma unroll
    for (int pi = 0; pi < 2; ++pi) {
        int p0 = (ptbase + pi) * 64;

        floatx4 acc[4][4];
        #pragma unroll
        for (int u = 0; u < 4; ++u)
            #pragma unroll
            for (int s2 = 0; s2 < 4; ++s2)
                #pragma unroll
                for (int r = 0; r < 4; ++r) acc[u][s2][r] = 0.0f;

        #pragma unroll
        for (int kt = 0; kt < 8; ++kt) {
            bf16x8 bfrag[4], afrag[4];
            #pragma unroll
            for (int s2 = 0; s2 < 4; ++s2) {
                int w = p0 + 16 * s2 + llo;
                int chunkp = (kt * 4 + lhi) ^ (llo & 7);   // w&7 == llo&7
                bfrag[s2] = *(const bf16x8*)&zt[w * 256 + chunkp * 8];
            }
            #pragma unroll
            for (int u = 0; u < 4; ++u)
                afrag[u] = *(const bf16x8*)(cwb + (size_t)(o_base + 16 * u + llo) * 256 + kt * 32 + lhi * 8);
            #pragma unroll
            for (int u = 0; u < 4; ++u)
                #pragma unroll
                for (int s2 = 0; s2 < 4; ++s2)
                    acc[u][s2] = __builtin_amdgcn_mfma_f32_16x16x32_bf16(afrag[u], bfrag[s2], acc[u][s2], 0, 0, 0);
        }

        // ---- epilogue: + S[o]*lnb[w], ReLU, store ----
        float lnbv[4];
        #pragma unroll
        for (int s2 = 0; s2 < 4; ++s2) lnbv[s2] = lnb[p0 + 16 * s2 + llo];
        #pragma unroll
        for (int u = 0; u < 4; ++u) {
            #pragma unroll
            for (int r = 0; r < 4; ++r) {
                int o = o_base + 16 * u + 4 * lhi + r;
                float so = S[o];
                #pragma unroll
                for (int s2 = 0; s2 < 4; ++s2) {
                    float v = acc[u][s2][r] + so * lnbv[s2];
                    v = v > 0.0f ? v : 0.0f;
                    ob[((size_t)o << 16) + p0 + 16 * s2 + llo] = v;
                }
            }
        }
    }
}

extern "C" void kernel_launch(void* const* d_in, const int* in_sizes, int n_in,
                              void* d_out, int out_size, void* d_ws, size_t ws_size,
                              hipStream_t stream) {
    const float* x   = (const float*)d_in[0];
    const float* y   = (const float*)d_in[1];
    const float* lnw = (const float*)d_in[2];
    const float* lnb = (const float*)d_in[3];
    const float* cw  = (const float*)d_in[4];
    float* out = (float*)d_out;

    // ws layout: cwb bf16 128 KiB | S 1 KiB
    unsigned short* cwb = (unsigned short*)d_ws;
    float* S            = (float*)((char*)d_ws + 131072);

    prep_kernel<<<256, 256, 0, stream>>>(cw, cwb, S);
    fused_kernel<<<1024, 512, 0, stream>>>(x, y, lnw, lnb, cwb, S, out);
}